// Round 7
// baseline (163.154 us; speedup 1.0000x reference)
//
#include <hip/hip_runtime.h>
#include <math.h>

// Problem constants (fixed by reference)
#define NPAR 2048   // B*Kp
#define KP   1024
#define MM   8
#define CC   256
#define KC   8192   // Kp*M
#define NCH  16384  // B*Kc

// ws offsets (float units). Packed AoS float4 per parent:
//  PKL = {L10, L20, L21, logdet}
//  PKI = {i0,  i1,  i2,  L00}
//  PKM = {mx,  my,  mz,  L11}
#define WS_PKL    0        // [NPAR][4]
#define WS_PKI    8192     // [NPAR][4]
#define WS_PKM    16384    // [NPAR][4]
#define WS_L22    24576    // [NPAR]
#define WS_MEANSP 26624    // [NPAR]
#define WS_SUMSQ  28672    // [NPAR]
#define WS_DOT8   30720    // [NPAR][8]
#define WS_APRIOR 47104    // [NPAR]
#define WS_EGATE  49152    // [8][256]
#define WS_UGATE  51200    // [256]
#define WS_C0GATE 51456    // [256]
#define WS_GEO    51712    // [8][3]
#define WS_MEANE  51736    // [8]
#define WS_SUMSQE 51744    // [8]
#define WS_NEIGH  51752    // [NPAR] ints
#define WS_PGATE  53824    // [NPAR][256]

// out offsets (float units)
#define OUT_S    0
#define OUT_MU   4194304
#define OUT_SIG  4243456
#define OUT_G    4390912
#define OUT_LOSS 4407296

__device__ __forceinline__ float siluf(float x){ return x / (1.f + expf(-x)); }
__device__ __forceinline__ float softplusf(float x){ return x > 20.f ? x : log1pf(expf(x)); }

// GEMM k-loop: acc[r] += xs[r][:] . W1[:][t], 8-deep register prefetch of W.
// xs reads are wave-uniform (broadcast, conflict-free).
template<int NR>
__device__ __forceinline__ void gemm_k(const float* __restrict__ W1, int t,
                                       const float xs[][256], float* acc) {
  float wn[8];
#pragma unroll
  for (int i = 0; i < 8; i++) wn[i] = W1[i * 256 + t];
  for (int kb = 0; kb < 256; kb += 8) {
    float wc[8];
#pragma unroll
    for (int i = 0; i < 8; i++) wc[i] = wn[i];
    if (kb + 8 < 256) {
#pragma unroll
      for (int i = 0; i < 8; i++) wn[i] = W1[(kb + 8 + i) * 256 + t];
    }
#pragma unroll
    for (int i = 0; i < 8; i += 4) {
#pragma unroll
      for (int r = 0; r < NR; r++) {
        float4 x = *(const float4*)&xs[r][kb + i];
        acc[r] += x.x * wc[i] + x.y * wc[i+1] + x.z * wc[i+2] + x.w * wc[i+3];
      }
    }
  }
}

// ================= Kernel P1: stats + Cholesky + misc (r5 version) =================
// blk 0..511   : per-parent row stats (4 parents/block, 1 wave each)
// blk 512..519 : Cholesky, thread = parent (packed float4 AoS writes)
// blk 520      : geo offsets + emb stats
__global__ __launch_bounds__(256) void kP1(const float* __restrict__ sp,
                                           const float* __restrict__ mu_p,
                                           const float* __restrict__ Sig,
                                           const float* __restrict__ emb,
                                           const float* __restrict__ geom_W,
                                           const float* __restrict__ geom_b,
                                           float* __restrict__ ws) {
  int blk = blockIdx.x;
  int t = threadIdx.x;
  if (blk < 512) {
    int pid  = blk * 4 + (t >> 6);
    int lane = t & 63;
    const float4 v = *(const float4*)(sp + pid * CC + lane * 4);
    float s  = v.x + v.y + v.z + v.w;
    float ss = v.x*v.x + v.y*v.y + v.z*v.z + v.w*v.w;
    float pd[8];
#pragma unroll
    for (int m = 0; m < 8; m++) {
      float4 e = *(const float4*)(emb + m * CC + lane * 4);
      pd[m] = v.x*e.x + v.y*e.y + v.z*e.z + v.w*e.w;
    }
#pragma unroll
    for (int o = 32; o > 0; o >>= 1) {
      s  += __shfl_xor(s, o);
      ss += __shfl_xor(ss, o);
#pragma unroll
      for (int m = 0; m < 8; m++) pd[m] += __shfl_xor(pd[m], o);
    }
    if (lane == 0) {
      ws[WS_MEANSP + pid] = s * (1.f / 256.f);
      ws[WS_SUMSQ + pid]  = ss;
#pragma unroll
      for (int m = 0; m < 8; m++) ws[WS_DOT8 + pid * 8 + m] = pd[m];
    }
  } else if (blk < 520) {
    int pid = (blk - 512) * 256 + t;   // 0..2047
    const float* S = Sig + pid * 9;
    float a00 = S[0] + 1e-6f, a10 = S[3], a11 = S[4] + 1e-6f;
    float a20 = S[6], a21 = S[7], a22 = S[8] + 1e-6f;
    float L00 = sqrtf(a00); float i0 = 1.f / L00;
    float L10 = a10 * i0, L20 = a20 * i0;
    float L11 = sqrtf(a11 - L10 * L10); float i1 = 1.f / L11;
    float L21 = (a21 - L20 * L10) * i1;
    float L22 = sqrtf(a22 - L20 * L20 - L21 * L21); float i2 = 1.f / L22;
    float logdet = 2.f * logf(L00 * L11 * L22);
    float4 pkl = {L10, L20, L21, logdet};
    float4 pki = {i0, i1, i2, L00};
    float4 pkm = {mu_p[pid*3+0], mu_p[pid*3+1], mu_p[pid*3+2], L11};
    *(float4*)(ws + WS_PKL + pid * 4) = pkl;
    *(float4*)(ws + WS_PKI + pid * 4) = pki;
    *(float4*)(ws + WS_PKM + pid * 4) = pkm;
    ws[WS_L22 + pid] = L22;
  } else {
    if (t < 192) {
      int o = t >> 3, lane8 = t & 7;
      int m = o / 3, d = o % 3;
      float acc = 0.f;
      for (int k = lane8; k < 256; k += 8) acc += emb[m * 256 + k] * geom_W[k * 3 + d];
      acc += __shfl_xor(acc, 1); acc += __shfl_xor(acc, 2); acc += __shfl_xor(acc, 4);
      if (lane8 == 0) ws[WS_GEO + o] = acc + geom_b[d];
    } else {
      int o = (t - 192) >> 3, lane8 = t & 7;
      if (o < 8) {
        float s = 0.f, ss = 0.f;
        for (int k = lane8; k < 256; k += 8) { float e = emb[o * 256 + k]; s += e; ss += e * e; }
        s  += __shfl_xor(s, 1);  s  += __shfl_xor(s, 2);  s  += __shfl_xor(s, 4);
        ss += __shfl_xor(ss, 1); ss += __shfl_xor(ss, 2); ss += __shfl_xor(ss, 4);
        if (lane8 == 0) { ws[WS_MEANE + o] = s * (1.f / 256.f); ws[WS_SUMSQE + o] = ss; }
      }
    }
  }
}

// ================= Kernel P2: neighbor search + head GEMMs (16 rows/block) =================
// blk 0..511  : best-neighbor search (packed float4 loads)
// blk 512..639: gate GEMM, 16 rows each, ln_g folded into X staging -> PGATE
// blk 640..767: prior GEMM, 16 data rows + 2 ln rows (u_p/c0_p in-block),
//               affine-LN epilogue + silu + W2 + rowsum + softplus -> APRIOR
// blk 768     : gate extras: E_gate (8 rows) + u_gate + c0_gate (10 rows)
__global__ __launch_bounds__(256) void kP2(const float* __restrict__ sp,
                                           const float* __restrict__ emb,
                                           const float* __restrict__ g_ln_g,
                                           const float* __restrict__ g_ln_b,
                                           const float* __restrict__ gW1,
                                           const float* __restrict__ gb1,
                                           const float* __restrict__ p_ln_g,
                                           const float* __restrict__ p_ln_b,
                                           const float* __restrict__ pW1,
                                           const float* __restrict__ pb1,
                                           const float* __restrict__ pW2,
                                           const float* __restrict__ pb2,
                                           float* __restrict__ ws) {
  __shared__ float xs[18][256];
  __shared__ float red[4][16];
  int blk = blockIdx.x;
  int t = threadIdx.x;

  if (blk < 512) {
    // ---- best neighbor (excluding self) ----
    int wv = blk * 4 + (t >> 6);   // parent row 0..2047
    int lane = t & 63;
    int b = wv >> 10;
    int j = wv & (KP - 1);
    const float4 qm = *(const float4*)(ws + WS_PKM + wv * 4);
    float qx = qm.x, qy = qm.y, qz = qm.z;
    float best = -3.4e38f; int bidx = 1 << 30;
    for (int it = 0; it < 16; it++) {
      int k = it * 64 + lane;
      int idx = b * KP + k;
      float4 pl = *(const float4*)(ws + WS_PKL + idx * 4);  // L10,L20,L21,ld
      float4 pi = *(const float4*)(ws + WS_PKI + idx * 4);  // i0,i1,i2,L00
      float4 pm = *(const float4*)(ws + WS_PKM + idx * 4);  // mx,my,mz,L11
      float dx = qx - pm.x, dy = qy - pm.y, dz = qz - pm.z;
      float y0 = dx * pi.x;
      float y1 = (dy - pl.x * y0) * pi.y;
      float y2 = (dz - pl.y * y0 - pl.z * y1) * pi.z;
      float sc = -0.5f * (y0*y0 + y1*y1 + y2*y2 + pl.w);
      if (k == j) sc = -3.4e38f;
      if (sc > best || (sc == best && k < bidx)) { best = sc; bidx = k; }
    }
#pragma unroll
    for (int o = 32; o > 0; o >>= 1) {
      float ob = __shfl_xor(best, o);
      int   oi = __shfl_xor(bidx, o);
      if (ob > best || (ob == best && oi < bidx)) { best = ob; bidx = oi; }
    }
    if (lane == 0) ((int*)ws)[WS_NEIGH + wv] = bidx;
  } else if (blk < 640) {
    // ---- gate GEMM: 16 rows ----
    int base = (blk - 512) * 16;
    float lg = g_ln_g[t];
#pragma unroll
    for (int r = 0; r < 16; r++) xs[r][t] = sp[(base + r) * 256 + t] * lg;
    __syncthreads();
    float acc[16];
#pragma unroll
    for (int r = 0; r < 16; r++) acc[r] = 0.f;
    gemm_k<16>(gW1, t, xs, acc);
#pragma unroll
    for (int r = 0; r < 16; r++) ws[WS_PGATE + (base + r) * 256 + t] = acc[r];
  } else if (blk < 768) {
    // ---- prior GEMM: 16 data rows + u_p row + c0_p row ----
    int base = (blk - 640) * 16;
    float lp = p_ln_g[t];
#pragma unroll
    for (int r = 0; r < 16; r++) xs[r][t] = sp[(base + r) * 256 + t] * lp;
    xs[16][t] = lp;          // u_p = p_ln_g @ pW1
    xs[17][t] = p_ln_b[t];   // c0_p raw = p_ln_b @ pW1
    __syncthreads();
    float acc[18];
#pragma unroll
    for (int r = 0; r < 18; r++) acc[r] = 0.f;
    gemm_k<18>(pW1, t, xs, acc);

    float up  = acc[16];
    float c0p = acc[17] + pb1[t];
    float w2 = pW2[t];
    float tv[16];
#pragma unroll
    for (int r = 0; r < 16; r++) {
      float mean = ws[WS_MEANSP + base + r];
      float var  = ws[WS_SUMSQ + base + r] * (1.f / 256.f) - mean * mean;
      float rstd = rsqrtf(var + 1e-5f);
      float h = (acc[r] - mean * up) * rstd + c0p;
      tv[r] = siluf(h) * w2;
    }
#pragma unroll
    for (int o = 32; o > 0; o >>= 1) {
#pragma unroll
      for (int r = 0; r < 16; r++) tv[r] += __shfl_xor(tv[r], o);
    }
    int wave = t >> 6;
    if ((t & 63) == 0) {
#pragma unroll
      for (int r = 0; r < 16; r++) red[wave][r] = tv[r];
    }
    __syncthreads();
    if (t < 16) {
      float sum = red[0][t] + red[1][t] + red[2][t] + red[3][t] + pb2[0];
      ws[WS_APRIOR + base + t] = softplusf(sum);
    }
  } else {
    // ---- gate extras: 8 emb rows + u_g + c0_g ----
    float lg = g_ln_g[t];
#pragma unroll
    for (int r = 0; r < 8; r++) xs[r][t] = emb[r * 256 + t] * lg;
    xs[8][t] = lg;
    xs[9][t] = g_ln_b[t];
    __syncthreads();
    float acc[10];
#pragma unroll
    for (int r = 0; r < 10; r++) acc[r] = 0.f;
    gemm_k<10>(gW1, t, xs, acc);
#pragma unroll
    for (int r = 0; r < 8; r++) ws[WS_EGATE + r * 256 + t] = acc[r];
    ws[WS_UGATE + t]  = acc[8];
    ws[WS_C0GATE + t] = acc[9] + gb1[t];
  }
}

// ================= Kernel D: per-child everything (one wave per child) =================
// NO device-scope atomics / fences here (round 3: per-block __threadfence
// across non-coherent XCD L2s serialized the kernel, 142 us vs ~12 us).
__global__ __launch_bounds__(256) void kD(const float* __restrict__ sp,
                                          const float* __restrict__ Sig,
                                          const float* __restrict__ mask,
                                          const float* __restrict__ xi_noise,
                                          const float* __restrict__ gW2,
                                          const float* __restrict__ gb2,
                                          const float* __restrict__ ws,
                                          float* __restrict__ out) {
  int wv   = blockIdx.x * 4 + (threadIdx.x >> 6);  // child 0..16383 (= b*Kc+i)
  int lane = threadIdx.x & 63;
  int b = wv >> 13;
  int i = wv & (KC - 1);
  int j = i >> 3;
  int m = i & 7;
  int prow = b * KP + j;

  // --- LN stats for gate_in row ---
  float mean_x = ws[WS_MEANSP + prow] + ws[WS_MEANE + m];
  float Ex2 = ws[WS_SUMSQ + prow] + 2.f * ws[WS_DOT8 + prow * 8 + m] + ws[WS_SUMSQE + m];
  float var = Ex2 * (1.f / 256.f) - mean_x * mean_x;
  float rstd = rsqrtf(var + 1e-5f);

  // --- gate head epilogue: pre = (P + E - mean*u)*rstd + c0; silu; dot W2 ---
  int c4 = lane * 4;
  float Pv[4], Ev[4], Uv[4], C0v[4], W2v[4];
  *(float4*)Pv  = *(const float4*)(ws + WS_PGATE + prow * 256 + c4);
  *(float4*)Ev  = *(const float4*)(ws + WS_EGATE + m * 256 + c4);
  *(float4*)Uv  = *(const float4*)(ws + WS_UGATE + c4);
  *(float4*)C0v = *(const float4*)(ws + WS_C0GATE + c4);
  *(float4*)W2v = *(const float4*)(gW2 + c4);
  float partial = 0.f;
#pragma unroll
  for (int q = 0; q < 4; q++) {
    float pre = (Pv[q] + Ev[q] - mean_x * Uv[q]) * rstd + C0v[q];
    partial += siluf(pre) * W2v[q];
  }
#pragma unroll
  for (int o = 32; o > 0; o >>= 1) partial += __shfl_xor(partial, o);
  float aP = ws[WS_APRIOR + prow];
  float bval = partial + gb2[0] + 0.5f * logf(aP + 1e-8f);
  float g = (1.f / (1.f + expf(-bval))) * mask[prow];

  // --- parent packed state ---
  const float4 plP = *(const float4*)(ws + WS_PKL + prow * 4);  // L10,L20,L21,ld
  const float4 piP = *(const float4*)(ws + WS_PKI + prow * 4);  // i0,i1,i2,L00
  const float4 pmP = *(const float4*)(ws + WS_PKM + prow * 4);  // mx,my,mz,L11
  float L22 = ws[WS_L22 + prow];

  // --- mu0 = mu_p + Lp @ (xi_noise + geo[m]) ---
  int xbase = (prow * 8 + m) * 3;
  float x0 = xi_noise[xbase + 0] + ws[WS_GEO + m * 3 + 0];
  float x1 = xi_noise[xbase + 1] + ws[WS_GEO + m * 3 + 1];
  float x2 = xi_noise[xbase + 2] + ws[WS_GEO + m * 3 + 2];
  float m0x = pmP.x + piP.w * x0;
  float m0y = pmP.y + plP.x * x0 + pmP.w * x1;
  float m0z = pmP.z + plP.y * x0 + plP.z * x1 + L22 * x2;

  // --- neighbors: r0 = self, r1 = precomputed best ---
  int n1 = ((const int*)ws)[WS_NEIGH + prow];
  int nrow1 = b * KP + n1;
  const float4 plN = *(const float4*)(ws + WS_PKL + nrow1 * 4);
  const float4 piN = *(const float4*)(ws + WS_PKI + nrow1 * 4);
  const float4 pmN = *(const float4*)(ws + WS_PKM + nrow1 * 4);

  float sc[2], nx[2], ny[2], nz[2];
  {
    float dx = m0x - pmP.x, dy = m0y - pmP.y, dz = m0z - pmP.z;
    float y0 = dx * piP.x;
    float y1 = (dy - plP.x * y0) * piP.y;
    float y2 = (dz - plP.y * y0 - plP.z * y1) * piP.z;
    sc[0] = -0.5f * (y0*y0 + y1*y1 + y2*y2 + plP.w);
    nx[0] = pmP.x; ny[0] = pmP.y; nz[0] = pmP.z;
  }
  {
    float dx = m0x - pmN.x, dy = m0y - pmN.y, dz = m0z - pmN.z;
    float y0 = dx * piN.x;
    float y1 = (dy - plN.x * y0) * piN.y;
    float y2 = (dz - plN.y * y0 - plN.z * y1) * piN.z;
    sc[1] = -0.5f * (y0*y0 + y1*y1 + y2*y2 + plN.w);
    nx[1] = pmN.x; ny[1] = pmN.y; nz[1] = pmN.z;
  }
  float mxs = fmaxf(sc[0], sc[1]);
  float e0 = expf(sc[0] - mxs), e1 = expf(sc[1] - mxs);
  float inv = 1.f / (e0 + e1);
  float w0 = e0 * inv, w1 = e1 * inv;

  float mcx = w0 * nx[0] + w1 * nx[1];
  float mcy = w0 * ny[0] + w1 * ny[1];
  float mcz = w0 * nz[0] + w1 * nz[1];

  // --- Sigma_child ---
  float d0x = nx[0] - mcx, d0y = ny[0] - mcy, d0z = nz[0] - mcz;
  float d1x = nx[1] - mcx, d1y = ny[1] - mcy, d1z = nz[1] - mcz;
  const float* S0 = Sig + prow * 9;
  const float* S1 = Sig + nrow1 * 9;
  const float PHIm2 = 0.390625f; // 1.6^-2
  float Sout[9];
  float dd0[3] = {d0x, d0y, d0z};
  float dd1[3] = {d1x, d1y, d1z};
#pragma unroll
  for (int a = 0; a < 3; a++)
#pragma unroll
    for (int e = 0; e < 3; e++) {
      float v = (w0 * S0[a*3+e] + w1 * S1[a*3+e]) * PHIm2
              + w0 * dd0[a] * dd0[e] + w1 * dd1[a] * dd1[e];
      if (a == e) v += 1e-4f;
      Sout[a*3+e] = v;
    }

  if (lane == 0) {
    float* om = out + OUT_MU + wv * 3;
    om[0] = mcx; om[1] = mcy; om[2] = mcz;
    out[OUT_G + wv] = g;
    float* os = out + OUT_SIG + wv * 9;
#pragma unroll
    for (int q = 0; q < 9; q++) os[q] = Sout[q];
  }

  // --- s_child0 row: g * (w0*s_self + w1*s_nei) ---
  float s0v[4], s1v[4], ov[4];
  *(float4*)s0v = *(const float4*)(sp + prow * 256 + c4);
  *(float4*)s1v = *(const float4*)(sp + nrow1 * 256 + c4);
  float gw0 = g * w0, gw1 = g * w1;
#pragma unroll
  for (int q = 0; q < 4; q++) ov[q] = gw0 * s0v[q] + gw1 * s1v[q];
  *(float4*)(out + OUT_S + wv * 256 + c4) = *(float4*)ov;
}

// ================= Kernel F: loss_count =================
__global__ __launch_bounds__(256) void kF(const float* __restrict__ out_in,
                                          const int* __restrict__ Kt,
                                          float* __restrict__ out) {
  __shared__ float red[4][2];
  int t = threadIdx.x;
  const float* gp = out_in + OUT_G;
  float s0 = 0.f, s1 = 0.f;
  for (int it = 0; it < 32; it++) {
    s0 += gp[it * 256 + t];
    s1 += gp[KC + it * 256 + t];
  }
#pragma unroll
  for (int o = 32; o > 0; o >>= 1) {
    s0 += __shfl_xor(s0, o);
    s1 += __shfl_xor(s1, o);
  }
  int wave = t >> 6;
  if ((t & 63) == 0) { red[wave][0] = s0; red[wave][1] = s1; }
  __syncthreads();
  if (t == 0) {
    float S0 = red[0][0] + red[1][0] + red[2][0] + red[3][0];
    float S1 = red[0][1] + red[1][1] + red[2][1] + red[3][1];
    float K = (float)Kt[0];
    float l0 = S0 - K, l1 = S1 - K;
    out[OUT_LOSS] = 0.5f * (l0 * l0 + l1 * l1);
  }
}

extern "C" void kernel_launch(void* const* d_in, const int* in_sizes, int n_in,
                              void* d_out, int out_size, void* d_ws, size_t ws_size,
                              hipStream_t stream) {
  const float* s_parent   = (const float*)d_in[0];
  const float* mu_p       = (const float*)d_in[1];
  const float* Sigma_p    = (const float*)d_in[2];
  const float* mask_par   = (const float*)d_in[3];
  const float* xi_noise   = (const float*)d_in[4];
  const float* emb        = (const float*)d_in[5];
  const float* gate_ln_g  = (const float*)d_in[6];
  const float* gate_ln_b  = (const float*)d_in[7];
  const float* gate_W1    = (const float*)d_in[8];
  const float* gate_b1    = (const float*)d_in[9];
  const float* gate_W2    = (const float*)d_in[10];
  const float* gate_b2    = (const float*)d_in[11];
  const float* prior_ln_g = (const float*)d_in[12];
  const float* prior_ln_b = (const float*)d_in[13];
  const float* prior_W1   = (const float*)d_in[14];
  const float* prior_b1   = (const float*)d_in[15];
  const float* prior_W2   = (const float*)d_in[16];
  const float* prior_b2   = (const float*)d_in[17];
  const float* geom_W     = (const float*)d_in[18];
  const float* geom_b     = (const float*)d_in[19];
  const int*   K_target   = (const int*)d_in[20];

  float* ws  = (float*)d_ws;
  float* out = (float*)d_out;

  kP1<<<521, 256, 0, stream>>>(s_parent, mu_p, Sigma_p, emb, geom_W, geom_b, ws);
  kP2<<<769, 256, 0, stream>>>(s_parent, emb, gate_ln_g, gate_ln_b, gate_W1, gate_b1,
                               prior_ln_g, prior_ln_b, prior_W1, prior_b1,
                               prior_W2, prior_b2, ws);
  kD<<<NCH / 4, 256, 0, stream>>>(s_parent, Sigma_p, mask_par, xi_noise,
                                  gate_W2, gate_b2, ws, out);
  kF<<<1, 256, 0, stream>>>(out, K_target, out);
}

// Round 8
// 162.228 us; speedup vs baseline: 1.0057x; 1.0057x over previous
//
#include <hip/hip_runtime.h>
#include <math.h>

// Problem constants (fixed by reference)
#define NPAR 2048   // B*Kp
#define KP   1024
#define MM   8
#define CC   256
#define KC   8192   // Kp*M
#define NCH  16384  // B*Kc

// ws offsets (float units). Packed AoS float4 per parent:
//  PKL = {L10, L20, L21, logdet}
//  PKI = {i0,  i1,  i2,  L00}
//  PKM = {mx,  my,  mz,  L11}
#define WS_PKL    0        // [NPAR][4]
#define WS_PKI    8192     // [NPAR][4]
#define WS_PKM    16384    // [NPAR][4]
#define WS_L22    24576    // [NPAR]
#define WS_MEANSP 26624    // [NPAR]
#define WS_SUMSQ  28672    // [NPAR]
#define WS_DOT8   30720    // [NPAR][8]
#define WS_EGATE  49152    // [8][256]
#define WS_UGATE  51200    // [256]
#define WS_C0GATE 51456    // [256]
#define WS_GEO    51712    // [8][3]
#define WS_MEANE  51736    // [8]
#define WS_SUMSQE 51744    // [8]
#define WS_NEIGH  51752    // [NPAR] ints
#define WS_UPRI   53824    // [256]
#define WS_C0PRI  54080    // [256] (includes pb1)
#define WS_PG     54336    // [NPAR][4][256] gate partials (slice-interleaved)
#define WS_PP     2151488  // [NPAR][4][256] prior partials

// out offsets (float units)
#define OUT_S    0
#define OUT_MU   4194304
#define OUT_SIG  4243456
#define OUT_G    4390912
#define OUT_LOSS 4407296

__device__ __forceinline__ float siluf(float x){ return x / (1.f + expf(-x)); }
__device__ __forceinline__ float softplusf(float x){ return x > 20.f ? x : log1pf(expf(x)); }

// Full-k GEMM loop (extras blocks only): acc[r] += xs[r][:] . W1[:][t]
template<int NR>
__device__ __forceinline__ void gemm_k(const float* __restrict__ W1, int t,
                                       const float xs[][256], float* acc) {
  float wn[8];
#pragma unroll
  for (int i = 0; i < 8; i++) wn[i] = W1[i * 256 + t];
  for (int kb = 0; kb < 256; kb += 8) {
    float wc[8];
#pragma unroll
    for (int i = 0; i < 8; i++) wc[i] = wn[i];
    if (kb + 8 < 256) {
#pragma unroll
      for (int i = 0; i < 8; i++) wn[i] = W1[(kb + 8 + i) * 256 + t];
    }
#pragma unroll
    for (int i = 0; i < 8; i += 4) {
#pragma unroll
      for (int r = 0; r < NR; r++) {
        float4 x = *(const float4*)&xs[r][kb + i];
        acc[r] += x.x * wc[i] + x.y * wc[i+1] + x.z * wc[i+2] + x.w * wc[i+3];
      }
    }
  }
}

// ================= Kernel P1: stats + Cholesky + misc =================
__global__ __launch_bounds__(256) void kP1(const float* __restrict__ sp,
                                           const float* __restrict__ mu_p,
                                           const float* __restrict__ Sig,
                                           const float* __restrict__ emb,
                                           const float* __restrict__ geom_W,
                                           const float* __restrict__ geom_b,
                                           float* __restrict__ ws) {
  int blk = blockIdx.x;
  int t = threadIdx.x;
  if (blk < 512) {
    int pid  = blk * 4 + (t >> 6);
    int lane = t & 63;
    const float4 v = *(const float4*)(sp + pid * CC + lane * 4);
    float s  = v.x + v.y + v.z + v.w;
    float ss = v.x*v.x + v.y*v.y + v.z*v.z + v.w*v.w;
    float pd[8];
#pragma unroll
    for (int m = 0; m < 8; m++) {
      float4 e = *(const float4*)(emb + m * CC + lane * 4);
      pd[m] = v.x*e.x + v.y*e.y + v.z*e.z + v.w*e.w;
    }
#pragma unroll
    for (int o = 32; o > 0; o >>= 1) {
      s  += __shfl_xor(s, o);
      ss += __shfl_xor(ss, o);
#pragma unroll
      for (int m = 0; m < 8; m++) pd[m] += __shfl_xor(pd[m], o);
    }
    if (lane == 0) {
      ws[WS_MEANSP + pid] = s * (1.f / 256.f);
      ws[WS_SUMSQ + pid]  = ss;
#pragma unroll
      for (int m = 0; m < 8; m++) ws[WS_DOT8 + pid * 8 + m] = pd[m];
    }
  } else if (blk < 520) {
    int pid = (blk - 512) * 256 + t;   // 0..2047
    const float* S = Sig + pid * 9;
    float a00 = S[0] + 1e-6f, a10 = S[3], a11 = S[4] + 1e-6f;
    float a20 = S[6], a21 = S[7], a22 = S[8] + 1e-6f;
    float L00 = sqrtf(a00); float i0 = 1.f / L00;
    float L10 = a10 * i0, L20 = a20 * i0;
    float L11 = sqrtf(a11 - L10 * L10); float i1 = 1.f / L11;
    float L21 = (a21 - L20 * L10) * i1;
    float L22 = sqrtf(a22 - L20 * L20 - L21 * L21); float i2 = 1.f / L22;
    float logdet = 2.f * logf(L00 * L11 * L22);
    float4 pkl = {L10, L20, L21, logdet};
    float4 pki = {i0, i1, i2, L00};
    float4 pkm = {mu_p[pid*3+0], mu_p[pid*3+1], mu_p[pid*3+2], L11};
    *(float4*)(ws + WS_PKL + pid * 4) = pkl;
    *(float4*)(ws + WS_PKI + pid * 4) = pki;
    *(float4*)(ws + WS_PKM + pid * 4) = pkm;
    ws[WS_L22 + pid] = L22;
  } else {
    if (t < 192) {
      int o = t >> 3, lane8 = t & 7;
      int m = o / 3, d = o % 3;
      float acc = 0.f;
      for (int k = lane8; k < 256; k += 8) acc += emb[m * 256 + k] * geom_W[k * 3 + d];
      acc += __shfl_xor(acc, 1); acc += __shfl_xor(acc, 2); acc += __shfl_xor(acc, 4);
      if (lane8 == 0) ws[WS_GEO + o] = acc + geom_b[d];
    } else {
      int o = (t - 192) >> 3, lane8 = t & 7;
      if (o < 8) {
        float s = 0.f, ss = 0.f;
        for (int k = lane8; k < 256; k += 8) { float e = emb[o * 256 + k]; s += e; ss += e * e; }
        s  += __shfl_xor(s, 1);  s  += __shfl_xor(s, 2);  s  += __shfl_xor(s, 4);
        ss += __shfl_xor(ss, 1); ss += __shfl_xor(ss, 2); ss += __shfl_xor(ss, 4);
        if (lane8 == 0) { ws[WS_MEANE + o] = s * (1.f / 256.f); ws[WS_SUMSQE + o] = ss; }
      }
    }
  }
}

// ================= Kernel P2: neighbor search + split-k head GEMMs =================
// blk 0..511    : best-neighbor search
// blk 512..1535 : gate GEMM partials, 8 rows x 64-k-slice each (4-way split-k)
// blk 1536..2559: prior GEMM partials, same geometry
// blk 2560      : gate extras full-k: E_gate (8) + u_g + c0_g
// blk 2561      : prior extras full-k: u_p + c0_p(+pb1)
__global__ __launch_bounds__(256) void kP2(const float* __restrict__ sp,
                                           const float* __restrict__ emb,
                                           const float* __restrict__ g_ln_g,
                                           const float* __restrict__ g_ln_b,
                                           const float* __restrict__ gW1,
                                           const float* __restrict__ gb1,
                                           const float* __restrict__ p_ln_g,
                                           const float* __restrict__ p_ln_b,
                                           const float* __restrict__ pW1,
                                           const float* __restrict__ pb1,
                                           float* __restrict__ ws) {
  __shared__ float xs[10][256];
  int blk = blockIdx.x;
  int t = threadIdx.x;

  if (blk < 512) {
    // ---- best neighbor (excluding self) ----
    int wv = blk * 4 + (t >> 6);   // parent row 0..2047
    int lane = t & 63;
    int b = wv >> 10;
    int j = wv & (KP - 1);
    const float4 qm = *(const float4*)(ws + WS_PKM + wv * 4);
    float qx = qm.x, qy = qm.y, qz = qm.z;
    float best = -3.4e38f; int bidx = 1 << 30;
    for (int it = 0; it < 16; it++) {
      int k = it * 64 + lane;
      int idx = b * KP + k;
      float4 pl = *(const float4*)(ws + WS_PKL + idx * 4);  // L10,L20,L21,ld
      float4 pi = *(const float4*)(ws + WS_PKI + idx * 4);  // i0,i1,i2,L00
      float4 pm = *(const float4*)(ws + WS_PKM + idx * 4);  // mx,my,mz,L11
      float dx = qx - pm.x, dy = qy - pm.y, dz = qz - pm.z;
      float y0 = dx * pi.x;
      float y1 = (dy - pl.x * y0) * pi.y;
      float y2 = (dz - pl.y * y0 - pl.z * y1) * pi.z;
      float sc = -0.5f * (y0*y0 + y1*y1 + y2*y2 + pl.w);
      if (k == j) sc = -3.4e38f;
      if (sc > best || (sc == best && k < bidx)) { best = sc; bidx = k; }
    }
#pragma unroll
    for (int o = 32; o > 0; o >>= 1) {
      float ob = __shfl_xor(best, o);
      int   oi = __shfl_xor(bidx, o);
      if (ob > best || (ob == best && oi < bidx)) { best = ob; bidx = oi; }
    }
    if (lane == 0) ((int*)ws)[WS_NEIGH + wv] = bidx;
  } else if (blk < 2560) {
    // ---- split-k GEMM partials ----
    int idx = blk - 512;               // 0..2047
    bool isGate = idx < 1024;
    int q2 = isGate ? idx : idx - 1024;
    const float* W1 = isGate ? gW1 : pW1;
    const float* ln = isGate ? g_ln_g : p_ln_g;
    int dst = isGate ? WS_PG : WS_PP;
    int rb = q2 >> 2, s = q2 & 3;
    int base = rb * 8, k0 = s * 64;
    float (*xs8)[64] = (float(*)[64])&xs[0][0];
#pragma unroll
    for (int u = 0; u < 2; u++) {
      int e = t + 256 * u;             // 0..511
      int r = e >> 6, kk = e & 63;
      xs8[r][kk] = sp[(base + r) * 256 + k0 + kk] * ln[k0 + kk];
    }
    __syncthreads();
    const float* W = W1 + k0 * 256;
    float acc[8] = {0,0,0,0,0,0,0,0};
    float wn[8];
#pragma unroll
    for (int i = 0; i < 8; i++) wn[i] = W[i * 256 + t];
    for (int kb = 0; kb < 64; kb += 8) {
      float wc[8];
#pragma unroll
      for (int i = 0; i < 8; i++) wc[i] = wn[i];
      if (kb + 8 < 64) {
#pragma unroll
        for (int i = 0; i < 8; i++) wn[i] = W[(kb + 8 + i) * 256 + t];
      }
#pragma unroll
      for (int i = 0; i < 8; i += 4) {
#pragma unroll
        for (int r = 0; r < 8; r++) {
          float4 x = *(const float4*)&xs8[r][kb + i];
          acc[r] += x.x * wc[i] + x.y * wc[i+1] + x.z * wc[i+2] + x.w * wc[i+3];
        }
      }
    }
#pragma unroll
    for (int r = 0; r < 8; r++)
      ws[dst + ((base + r) * 4 + s) * 256 + t] = acc[r];
  } else if (blk == 2560) {
    // ---- gate extras: 8 emb rows + u_g + c0_g, full k ----
    float lg = g_ln_g[t];
#pragma unroll
    for (int r = 0; r < 8; r++) xs[r][t] = emb[r * 256 + t] * lg;
    xs[8][t] = lg;
    xs[9][t] = g_ln_b[t];
    __syncthreads();
    float acc[10];
#pragma unroll
    for (int r = 0; r < 10; r++) acc[r] = 0.f;
    gemm_k<10>(gW1, t, xs, acc);
#pragma unroll
    for (int r = 0; r < 8; r++) ws[WS_EGATE + r * 256 + t] = acc[r];
    ws[WS_UGATE + t]  = acc[8];
    ws[WS_C0GATE + t] = acc[9] + gb1[t];
  } else {
    // ---- prior extras: u_p + c0_p, full k ----
    xs[0][t] = p_ln_g[t];
    xs[1][t] = p_ln_b[t];
    __syncthreads();
    float acc[2] = {0.f, 0.f};
    gemm_k<2>(pW1, t, xs, acc);
    ws[WS_UPRI  + t] = acc[0];
    ws[WS_C0PRI + t] = acc[1] + pb1[t];
  }
}

// ================= Kernel D: per-child everything (one wave per child) =================
// NO device-scope atomics / fences (round 3 lesson). Prior-head epilogue is
// computed inline per wave from split-k partials (8x redundant per parent, cheap).
__global__ __launch_bounds__(256) void kD(const float* __restrict__ sp,
                                          const float* __restrict__ Sig,
                                          const float* __restrict__ mask,
                                          const float* __restrict__ xi_noise,
                                          const float* __restrict__ gW2,
                                          const float* __restrict__ gb2,
                                          const float* __restrict__ pW2,
                                          const float* __restrict__ pb2,
                                          const float* __restrict__ ws,
                                          float* __restrict__ out) {
  int wv   = blockIdx.x * 4 + (threadIdx.x >> 6);  // child 0..16383 (= b*Kc+i)
  int lane = threadIdx.x & 63;
  int b = wv >> 13;
  int i = wv & (KC - 1);
  int j = i >> 3;
  int m = i & 7;
  int prow = b * KP + j;
  int c4 = lane * 4;

  // --- parent LN stats (shared by both heads) ---
  float meanP = ws[WS_MEANSP + prow];
  float varP  = ws[WS_SUMSQ + prow] * (1.f / 256.f) - meanP * meanP;
  float rstdP = rsqrtf(varP + 1e-5f);

  // --- prior head epilogue from split-k partials ---
  float PPv[4] = {0,0,0,0};
#pragma unroll
  for (int s = 0; s < 4; s++) {
    float4 pp = *(const float4*)(ws + WS_PP + ((prow * 4 + s) << 8) + c4);
    PPv[0] += pp.x; PPv[1] += pp.y; PPv[2] += pp.z; PPv[3] += pp.w;
  }
  float4 upv  = *(const float4*)(ws + WS_UPRI + c4);
  float4 c0pv = *(const float4*)(ws + WS_C0PRI + c4);
  float4 w2pv = *(const float4*)(pW2 + c4);
  float upr[4]  = {upv.x, upv.y, upv.z, upv.w};
  float c0pr[4] = {c0pv.x, c0pv.y, c0pv.z, c0pv.w};
  float w2pr[4] = {w2pv.x, w2pv.y, w2pv.z, w2pv.w};
  float psum = 0.f;
#pragma unroll
  for (int q = 0; q < 4; q++) {
    float h = (PPv[q] - meanP * upr[q]) * rstdP + c0pr[q];
    psum += siluf(h) * w2pr[q];
  }
#pragma unroll
  for (int o = 32; o > 0; o >>= 1) psum += __shfl_xor(psum, o);
  float aP = softplusf(psum + pb2[0]);

  // --- gate-in LN stats ---
  float mean_x = meanP + ws[WS_MEANE + m];
  float Ex2 = ws[WS_SUMSQ + prow] + 2.f * ws[WS_DOT8 + prow * 8 + m] + ws[WS_SUMSQE + m];
  float var = Ex2 * (1.f / 256.f) - mean_x * mean_x;
  float rstd = rsqrtf(var + 1e-5f);

  // --- gate head epilogue ---
  float Pv[4] = {0,0,0,0};
#pragma unroll
  for (int s = 0; s < 4; s++) {
    float4 pg = *(const float4*)(ws + WS_PG + ((prow * 4 + s) << 8) + c4);
    Pv[0] += pg.x; Pv[1] += pg.y; Pv[2] += pg.z; Pv[3] += pg.w;
  }
  float Ev[4], Uv[4], C0v[4], W2v[4];
  *(float4*)Ev  = *(const float4*)(ws + WS_EGATE + m * 256 + c4);
  *(float4*)Uv  = *(const float4*)(ws + WS_UGATE + c4);
  *(float4*)C0v = *(const float4*)(ws + WS_C0GATE + c4);
  *(float4*)W2v = *(const float4*)(gW2 + c4);
  float partial = 0.f;
#pragma unroll
  for (int q = 0; q < 4; q++) {
    float pre = (Pv[q] + Ev[q] - mean_x * Uv[q]) * rstd + C0v[q];
    partial += siluf(pre) * W2v[q];
  }
#pragma unroll
  for (int o = 32; o > 0; o >>= 1) partial += __shfl_xor(partial, o);
  float bval = partial + gb2[0] + 0.5f * logf(aP + 1e-8f);
  float g = (1.f / (1.f + expf(-bval))) * mask[prow];

  // --- parent packed state ---
  const float4 plP = *(const float4*)(ws + WS_PKL + prow * 4);  // L10,L20,L21,ld
  const float4 piP = *(const float4*)(ws + WS_PKI + prow * 4);  // i0,i1,i2,L00
  const float4 pmP = *(const float4*)(ws + WS_PKM + prow * 4);  // mx,my,mz,L11
  float L22 = ws[WS_L22 + prow];

  // --- mu0 = mu_p + Lp @ (xi_noise + geo[m]) ---
  int xbase = (prow * 8 + m) * 3;
  float x0 = xi_noise[xbase + 0] + ws[WS_GEO + m * 3 + 0];
  float x1 = xi_noise[xbase + 1] + ws[WS_GEO + m * 3 + 1];
  float x2 = xi_noise[xbase + 2] + ws[WS_GEO + m * 3 + 2];
  float m0x = pmP.x + piP.w * x0;
  float m0y = pmP.y + plP.x * x0 + pmP.w * x1;
  float m0z = pmP.z + plP.y * x0 + plP.z * x1 + L22 * x2;

  // --- neighbors: r0 = self, r1 = precomputed best ---
  int n1 = ((const int*)ws)[WS_NEIGH + prow];
  int nrow1 = b * KP + n1;
  const float4 plN = *(const float4*)(ws + WS_PKL + nrow1 * 4);
  const float4 piN = *(const float4*)(ws + WS_PKI + nrow1 * 4);
  const float4 pmN = *(const float4*)(ws + WS_PKM + nrow1 * 4);

  float sc[2], nx[2], ny[2], nz[2];
  {
    float dx = m0x - pmP.x, dy = m0y - pmP.y, dz = m0z - pmP.z;
    float y0 = dx * piP.x;
    float y1 = (dy - plP.x * y0) * piP.y;
    float y2 = (dz - plP.y * y0 - plP.z * y1) * piP.z;
    sc[0] = -0.5f * (y0*y0 + y1*y1 + y2*y2 + plP.w);
    nx[0] = pmP.x; ny[0] = pmP.y; nz[0] = pmP.z;
  }
  {
    float dx = m0x - pmN.x, dy = m0y - pmN.y, dz = m0z - pmN.z;
    float y0 = dx * piN.x;
    float y1 = (dy - plN.x * y0) * piN.y;
    float y2 = (dz - plN.y * y0 - plN.z * y1) * piN.z;
    sc[1] = -0.5f * (y0*y0 + y1*y1 + y2*y2 + plN.w);
    nx[1] = pmN.x; ny[1] = pmN.y; nz[1] = pmN.z;
  }
  float mxs = fmaxf(sc[0], sc[1]);
  float e0 = expf(sc[0] - mxs), e1 = expf(sc[1] - mxs);
  float inv = 1.f / (e0 + e1);
  float w0 = e0 * inv, w1 = e1 * inv;

  float mcx = w0 * nx[0] + w1 * nx[1];
  float mcy = w0 * ny[0] + w1 * ny[1];
  float mcz = w0 * nz[0] + w1 * nz[1];

  // --- Sigma_child ---
  float d0x = nx[0] - mcx, d0y = ny[0] - mcy, d0z = nz[0] - mcz;
  float d1x = nx[1] - mcx, d1y = ny[1] - mcy, d1z = nz[1] - mcz;
  const float* S0 = Sig + prow * 9;
  const float* S1 = Sig + nrow1 * 9;
  const float PHIm2 = 0.390625f; // 1.6^-2
  float Sout[9];
  float dd0[3] = {d0x, d0y, d0z};
  float dd1[3] = {d1x, d1y, d1z};
#pragma unroll
  for (int a = 0; a < 3; a++)
#pragma unroll
    for (int e = 0; e < 3; e++) {
      float v = (w0 * S0[a*3+e] + w1 * S1[a*3+e]) * PHIm2
              + w0 * dd0[a] * dd0[e] + w1 * dd1[a] * dd1[e];
      if (a == e) v += 1e-4f;
      Sout[a*3+e] = v;
    }

  if (lane == 0) {
    float* om = out + OUT_MU + wv * 3;
    om[0] = mcx; om[1] = mcy; om[2] = mcz;
    out[OUT_G + wv] = g;
    float* os = out + OUT_SIG + wv * 9;
#pragma unroll
    for (int q = 0; q < 9; q++) os[q] = Sout[q];
  }

  // --- s_child0 row: g * (w0*s_self + w1*s_nei) ---
  float s0v[4], s1v[4], ov[4];
  *(float4*)s0v = *(const float4*)(sp + prow * 256 + c4);
  *(float4*)s1v = *(const float4*)(sp + nrow1 * 256 + c4);
  float gw0 = g * w0, gw1 = g * w1;
#pragma unroll
  for (int q = 0; q < 4; q++) ov[q] = gw0 * s0v[q] + gw1 * s1v[q];
  *(float4*)(out + OUT_S + wv * 256 + c4) = *(float4*)ov;
}

// ================= Kernel F: loss_count =================
__global__ __launch_bounds__(256) void kF(const float* __restrict__ out_in,
                                          const int* __restrict__ Kt,
                                          float* __restrict__ out) {
  __shared__ float red[4][2];
  int t = threadIdx.x;
  const float* gp = out_in + OUT_G;
  float s0 = 0.f, s1 = 0.f;
  for (int it = 0; it < 32; it++) {
    s0 += gp[it * 256 + t];
    s1 += gp[KC + it * 256 + t];
  }
#pragma unroll
  for (int o = 32; o > 0; o >>= 1) {
    s0 += __shfl_xor(s0, o);
    s1 += __shfl_xor(s1, o);
  }
  int wave = t >> 6;
  if ((t & 63) == 0) { red[wave][0] = s0; red[wave][1] = s1; }
  __syncthreads();
  if (t == 0) {
    float S0 = red[0][0] + red[1][0] + red[2][0] + red[3][0];
    float S1 = red[0][1] + red[1][1] + red[2][1] + red[3][1];
    float K = (float)Kt[0];
    float l0 = S0 - K, l1 = S1 - K;
    out[OUT_LOSS] = 0.5f * (l0 * l0 + l1 * l1);
  }
}

extern "C" void kernel_launch(void* const* d_in, const int* in_sizes, int n_in,
                              void* d_out, int out_size, void* d_ws, size_t ws_size,
                              hipStream_t stream) {
  const float* s_parent   = (const float*)d_in[0];
  const float* mu_p       = (const float*)d_in[1];
  const float* Sigma_p    = (const float*)d_in[2];
  const float* mask_par   = (const float*)d_in[3];
  const float* xi_noise   = (const float*)d_in[4];
  const float* emb        = (const float*)d_in[5];
  const float* gate_ln_g  = (const float*)d_in[6];
  const float* gate_ln_b  = (const float*)d_in[7];
  const float* gate_W1    = (const float*)d_in[8];
  const float* gate_b1    = (const float*)d_in[9];
  const float* gate_W2    = (const float*)d_in[10];
  const float* gate_b2    = (const float*)d_in[11];
  const float* prior_ln_g = (const float*)d_in[12];
  const float* prior_ln_b = (const float*)d_in[13];
  const float* prior_W1   = (const float*)d_in[14];
  const float* prior_b1   = (const float*)d_in[15];
  const float* prior_W2   = (const float*)d_in[16];
  const float* prior_b2   = (const float*)d_in[17];
  const float* geom_W     = (const float*)d_in[18];
  const float* geom_b     = (const float*)d_in[19];
  const int*   K_target   = (const int*)d_in[20];

  float* ws  = (float*)d_ws;
  float* out = (float*)d_out;

  kP1<<<521, 256, 0, stream>>>(s_parent, mu_p, Sigma_p, emb, geom_W, geom_b, ws);
  kP2<<<2562, 256, 0, stream>>>(s_parent, emb, gate_ln_g, gate_ln_b, gate_W1, gate_b1,
                                prior_ln_g, prior_ln_b, prior_W1, prior_b1, ws);
  kD<<<NCH / 4, 256, 0, stream>>>(s_parent, Sigma_p, mask_par, xi_noise,
                                  gate_W2, gate_b2, prior_W2, prior_b2, ws, out);
  kF<<<1, 256, 0, stream>>>(out, K_target, out);
}

// Round 9
// 152.590 us; speedup vs baseline: 1.0692x; 1.0632x over previous
//
#include <hip/hip_runtime.h>
#include <math.h>

// Problem constants (fixed by reference)
#define NPAR 2048   // B*Kp
#define KP   1024
#define MM   8
#define CC   256
#define KC   8192   // Kp*M
#define NCH  16384  // B*Kc

// ws offsets (float units). Packed AoS float4 per parent:
//  PKL = {L10, L20, L21, logdet}
//  PKI = {i0,  i1,  i2,  L00}
//  PKM = {mx,  my,  mz,  L11}
#define WS_PKL    0        // [NPAR][4]
#define WS_PKI    8192     // [NPAR][4]
#define WS_PKM    16384    // [NPAR][4]
#define WS_L22    24576    // [NPAR]
#define WS_MEANSP 26624    // [NPAR]
#define WS_SUMSQ  28672    // [NPAR]
#define WS_DOT8   30720    // [NPAR][8]
#define WS_APRIOR 47104    // [NPAR]
#define WS_EGATE  49152    // [8][256]
#define WS_UGATE  51200    // [256]
#define WS_C0GATE 51456    // [256]
#define WS_GEO    51712    // [8][3]
#define WS_MEANE  51736    // [8]
#define WS_SUMSQE 51744    // [8]
#define WS_NEIGH  51752    // [NPAR] ints
#define WS_PGATE  53824    // [NPAR][256]

// out offsets (float units)
#define OUT_S    0
#define OUT_MU   4194304
#define OUT_SIG  4243456
#define OUT_G    4390912
#define OUT_LOSS 4407296

__device__ __forceinline__ float siluf(float x){ return x / (1.f + expf(-x)); }
__device__ __forceinline__ float softplusf(float x){ return x > 20.f ? x : log1pf(expf(x)); }

// GEMM k-loop: acc[r] += xs[r][:] . W1[:][t], 16-deep register prefetch of W.
// 16 outstanding global loads per wave cover L2 latency (~200-300 cyc) with
// only 2 waves/SIMD resident. xs reads are wave-uniform broadcasts.
template<int NR>
__device__ __forceinline__ void gemm_k(const float* __restrict__ W1, int t,
                                       const float xs[][256], float* acc) {
  float wn[16];
#pragma unroll
  for (int i = 0; i < 16; i++) wn[i] = W1[i * 256 + t];
  for (int kb = 0; kb < 256; kb += 16) {
    float wc[16];
#pragma unroll
    for (int i = 0; i < 16; i++) wc[i] = wn[i];
    if (kb + 16 < 256) {
#pragma unroll
      for (int i = 0; i < 16; i++) wn[i] = W1[(kb + 16 + i) * 256 + t];
    }
#pragma unroll
    for (int i = 0; i < 16; i += 4) {
#pragma unroll
      for (int r = 0; r < NR; r++) {
        float4 x = *(const float4*)&xs[r][kb + i];
        acc[r] += x.x * wc[i] + x.y * wc[i+1] + x.z * wc[i+2] + x.w * wc[i+3];
      }
    }
  }
}

// ================= Kernel P1: stats + Cholesky + misc =================
// blk 0..511   : per-parent row stats (4 parents/block, 1 wave each)
// blk 512..519 : Cholesky, thread = parent (packed float4 AoS writes)
// blk 520      : geo offsets + emb stats
__global__ __launch_bounds__(256) void kP1(const float* __restrict__ sp,
                                           const float* __restrict__ mu_p,
                                           const float* __restrict__ Sig,
                                           const float* __restrict__ emb,
                                           const float* __restrict__ geom_W,
                                           const float* __restrict__ geom_b,
                                           float* __restrict__ ws) {
  int blk = blockIdx.x;
  int t = threadIdx.x;
  if (blk < 512) {
    int pid  = blk * 4 + (t >> 6);
    int lane = t & 63;
    const float4 v = *(const float4*)(sp + pid * CC + lane * 4);
    float s  = v.x + v.y + v.z + v.w;
    float ss = v.x*v.x + v.y*v.y + v.z*v.z + v.w*v.w;
    float pd[8];
#pragma unroll
    for (int m = 0; m < 8; m++) {
      float4 e = *(const float4*)(emb + m * CC + lane * 4);
      pd[m] = v.x*e.x + v.y*e.y + v.z*e.z + v.w*e.w;
    }
#pragma unroll
    for (int o = 32; o > 0; o >>= 1) {
      s  += __shfl_xor(s, o);
      ss += __shfl_xor(ss, o);
#pragma unroll
      for (int m = 0; m < 8; m++) pd[m] += __shfl_xor(pd[m], o);
    }
    if (lane == 0) {
      ws[WS_MEANSP + pid] = s * (1.f / 256.f);
      ws[WS_SUMSQ + pid]  = ss;
#pragma unroll
      for (int m = 0; m < 8; m++) ws[WS_DOT8 + pid * 8 + m] = pd[m];
    }
  } else if (blk < 520) {
    int pid = (blk - 512) * 256 + t;   // 0..2047
    const float* S = Sig + pid * 9;
    float a00 = S[0] + 1e-6f, a10 = S[3], a11 = S[4] + 1e-6f;
    float a20 = S[6], a21 = S[7], a22 = S[8] + 1e-6f;
    float L00 = sqrtf(a00); float i0 = 1.f / L00;
    float L10 = a10 * i0, L20 = a20 * i0;
    float L11 = sqrtf(a11 - L10 * L10); float i1 = 1.f / L11;
    float L21 = (a21 - L20 * L10) * i1;
    float L22 = sqrtf(a22 - L20 * L20 - L21 * L21); float i2 = 1.f / L22;
    float logdet = 2.f * logf(L00 * L11 * L22);
    float4 pkl = {L10, L20, L21, logdet};
    float4 pki = {i0, i1, i2, L00};
    float4 pkm = {mu_p[pid*3+0], mu_p[pid*3+1], mu_p[pid*3+2], L11};
    *(float4*)(ws + WS_PKL + pid * 4) = pkl;
    *(float4*)(ws + WS_PKI + pid * 4) = pki;
    *(float4*)(ws + WS_PKM + pid * 4) = pkm;
    ws[WS_L22 + pid] = L22;
  } else {
    if (t < 192) {
      int o = t >> 3, lane8 = t & 7;
      int m = o / 3, d = o % 3;
      float acc = 0.f;
      for (int k = lane8; k < 256; k += 8) acc += emb[m * 256 + k] * geom_W[k * 3 + d];
      acc += __shfl_xor(acc, 1); acc += __shfl_xor(acc, 2); acc += __shfl_xor(acc, 4);
      if (lane8 == 0) ws[WS_GEO + o] = acc + geom_b[d];
    } else {
      int o = (t - 192) >> 3, lane8 = t & 7;
      if (o < 8) {
        float s = 0.f, ss = 0.f;
        for (int k = lane8; k < 256; k += 8) { float e = emb[o * 256 + k]; s += e; ss += e * e; }
        s  += __shfl_xor(s, 1);  s  += __shfl_xor(s, 2);  s  += __shfl_xor(s, 4);
        ss += __shfl_xor(ss, 1); ss += __shfl_xor(ss, 2); ss += __shfl_xor(ss, 4);
        if (lane8 == 0) { ws[WS_MEANE + o] = s * (1.f / 256.f); ws[WS_SUMSQE + o] = ss; }
      }
    }
  }
}

// ================= Kernel P2: neighbor search + head GEMMs (8 rows/block) =================
// blk 0..511   : best-neighbor search (packed float4 loads)
// blk 512..767 : gate GEMM, 8 rows, ln_g folded into X staging -> PGATE
// blk 768..1023: prior GEMM, 8 rows, LN applied at staging (stats from kP1),
//                epilogue silu+W2+rowsum+softplus -> APRIOR
// blk 1024     : gate extras: E_gate (8 rows) + u_gate + c0_gate
__global__ __launch_bounds__(256) void kP2(const float* __restrict__ sp,
                                           const float* __restrict__ emb,
                                           const float* __restrict__ g_ln_g,
                                           const float* __restrict__ g_ln_b,
                                           const float* __restrict__ gW1,
                                           const float* __restrict__ gb1,
                                           const float* __restrict__ p_ln_g,
                                           const float* __restrict__ p_ln_b,
                                           const float* __restrict__ pW1,
                                           const float* __restrict__ pb1,
                                           const float* __restrict__ pW2,
                                           const float* __restrict__ pb2,
                                           float* __restrict__ ws) {
  __shared__ float xs[10][256];
  __shared__ float red[4][8];
  int blk = blockIdx.x;
  int t = threadIdx.x;

  if (blk < 512) {
    // ---- best neighbor (excluding self) ----
    int wv = blk * 4 + (t >> 6);   // parent row 0..2047
    int lane = t & 63;
    int b = wv >> 10;
    int j = wv & (KP - 1);
    const float4 qm = *(const float4*)(ws + WS_PKM + wv * 4);
    float qx = qm.x, qy = qm.y, qz = qm.z;
    float best = -3.4e38f; int bidx = 1 << 30;
    for (int it = 0; it < 16; it++) {
      int k = it * 64 + lane;
      int idx = b * KP + k;
      float4 pl = *(const float4*)(ws + WS_PKL + idx * 4);  // L10,L20,L21,ld
      float4 pi = *(const float4*)(ws + WS_PKI + idx * 4);  // i0,i1,i2,L00
      float4 pm = *(const float4*)(ws + WS_PKM + idx * 4);  // mx,my,mz,L11
      float dx = qx - pm.x, dy = qy - pm.y, dz = qz - pm.z;
      float y0 = dx * pi.x;
      float y1 = (dy - pl.x * y0) * pi.y;
      float y2 = (dz - pl.y * y0 - pl.z * y1) * pi.z;
      float sc = -0.5f * (y0*y0 + y1*y1 + y2*y2 + pl.w);
      if (k == j) sc = -3.4e38f;
      if (sc > best || (sc == best && k < bidx)) { best = sc; bidx = k; }
    }
#pragma unroll
    for (int o = 32; o > 0; o >>= 1) {
      float ob = __shfl_xor(best, o);
      int   oi = __shfl_xor(bidx, o);
      if (ob > best || (ob == best && oi < bidx)) { best = ob; bidx = oi; }
    }
    if (lane == 0) ((int*)ws)[WS_NEIGH + wv] = bidx;
  } else if (blk < 768) {
    // ---- gate GEMM: 8 rows ----
    int base = (blk - 512) * 8;
    float lg = g_ln_g[t];
#pragma unroll
    for (int r = 0; r < 8; r++) xs[r][t] = sp[(base + r) * 256 + t] * lg;
    __syncthreads();
    float acc[8] = {0,0,0,0,0,0,0,0};
    gemm_k<8>(gW1, t, xs, acc);
#pragma unroll
    for (int r = 0; r < 8; r++) ws[WS_PGATE + (base + r) * 256 + t] = acc[r];
  } else if (blk < 1024) {
    // ---- prior GEMM: 8 rows, LN at staging (stats from kP1) ----
    int base = (blk - 768) * 8;
    float pg = p_ln_g[t], pbv = p_ln_b[t];
#pragma unroll
    for (int r = 0; r < 8; r++) {
      int row = base + r;
      float mean = ws[WS_MEANSP + row];
      float var  = ws[WS_SUMSQ + row] * (1.f / 256.f) - mean * mean;
      float rstd = rsqrtf(var + 1e-5f);
      xs[r][t] = (sp[row * 256 + t] - mean) * rstd * pg + pbv;
    }
    __syncthreads();
    float acc[8] = {0,0,0,0,0,0,0,0};
    gemm_k<8>(pW1, t, xs, acc);
    float b1 = pb1[t], w2 = pW2[t];
    float tv[8];
#pragma unroll
    for (int r = 0; r < 8; r++) {
      float h = acc[r] + b1;
      tv[r] = siluf(h) * w2;
    }
#pragma unroll
    for (int o = 32; o > 0; o >>= 1) {
#pragma unroll
      for (int r = 0; r < 8; r++) tv[r] += __shfl_xor(tv[r], o);
    }
    int wave = t >> 6;
    if ((t & 63) == 0) {
#pragma unroll
      for (int r = 0; r < 8; r++) red[wave][r] = tv[r];
    }
    __syncthreads();
    if (t < 8) {
      float sum = red[0][t] + red[1][t] + red[2][t] + red[3][t] + pb2[0];
      ws[WS_APRIOR + base + t] = softplusf(sum);
    }
  } else {
    // ---- gate extras: 8 emb rows + u_g + c0_g ----
    float lg = g_ln_g[t];
#pragma unroll
    for (int r = 0; r < 8; r++) xs[r][t] = emb[r * 256 + t] * lg;
    xs[8][t] = lg;
    xs[9][t] = g_ln_b[t];
    __syncthreads();
    float acc[10];
#pragma unroll
    for (int r = 0; r < 10; r++) acc[r] = 0.f;
    gemm_k<10>(gW1, t, xs, acc);
#pragma unroll
    for (int r = 0; r < 8; r++) ws[WS_EGATE + r * 256 + t] = acc[r];
    ws[WS_UGATE + t]  = acc[8];
    ws[WS_C0GATE + t] = acc[9] + gb1[t];
  }
}

// ================= Kernel D: per-child everything (one wave per child) =================
// NO device-scope atomics / fences (round 3: per-block __threadfence across
// non-coherent XCD L2s serialized the kernel, 142 us vs ~12 us).
__global__ __launch_bounds__(256) void kD(const float* __restrict__ sp,
                                          const float* __restrict__ Sig,
                                          const float* __restrict__ mask,
                                          const float* __restrict__ xi_noise,
                                          const float* __restrict__ gW2,
                                          const float* __restrict__ gb2,
                                          const float* __restrict__ ws,
                                          float* __restrict__ out) {
  int wv   = blockIdx.x * 4 + (threadIdx.x >> 6);  // child 0..16383 (= b*Kc+i)
  int lane = threadIdx.x & 63;
  int b = wv >> 13;
  int i = wv & (KC - 1);
  int j = i >> 3;
  int m = i & 7;
  int prow = b * KP + j;

  // --- LN stats for gate_in row ---
  float mean_x = ws[WS_MEANSP + prow] + ws[WS_MEANE + m];
  float Ex2 = ws[WS_SUMSQ + prow] + 2.f * ws[WS_DOT8 + prow * 8 + m] + ws[WS_SUMSQE + m];
  float var = Ex2 * (1.f / 256.f) - mean_x * mean_x;
  float rstd = rsqrtf(var + 1e-5f);

  // --- gate head epilogue: pre = (P + E - mean*u)*rstd + c0; silu; dot W2 ---
  int c4 = lane * 4;
  float Pv[4], Ev[4], Uv[4], C0v[4], W2v[4];
  *(float4*)Pv  = *(const float4*)(ws + WS_PGATE + prow * 256 + c4);
  *(float4*)Ev  = *(const float4*)(ws + WS_EGATE + m * 256 + c4);
  *(float4*)Uv  = *(const float4*)(ws + WS_UGATE + c4);
  *(float4*)C0v = *(const float4*)(ws + WS_C0GATE + c4);
  *(float4*)W2v = *(const float4*)(gW2 + c4);
  float partial = 0.f;
#pragma unroll
  for (int q = 0; q < 4; q++) {
    float pre = (Pv[q] + Ev[q] - mean_x * Uv[q]) * rstd + C0v[q];
    partial += siluf(pre) * W2v[q];
  }
#pragma unroll
  for (int o = 32; o > 0; o >>= 1) partial += __shfl_xor(partial, o);
  float aP = ws[WS_APRIOR + prow];
  float bval = partial + gb2[0] + 0.5f * logf(aP + 1e-8f);
  float g = (1.f / (1.f + expf(-bval))) * mask[prow];

  // --- parent packed state ---
  const float4 plP = *(const float4*)(ws + WS_PKL + prow * 4);  // L10,L20,L21,ld
  const float4 piP = *(const float4*)(ws + WS_PKI + prow * 4);  // i0,i1,i2,L00
  const float4 pmP = *(const float4*)(ws + WS_PKM + prow * 4);  // mx,my,mz,L11
  float L22 = ws[WS_L22 + prow];

  // --- mu0 = mu_p + Lp @ (xi_noise + geo[m]) ---
  int xbase = (prow * 8 + m) * 3;
  float x0 = xi_noise[xbase + 0] + ws[WS_GEO + m * 3 + 0];
  float x1 = xi_noise[xbase + 1] + ws[WS_GEO + m * 3 + 1];
  float x2 = xi_noise[xbase + 2] + ws[WS_GEO + m * 3 + 2];
  float m0x = pmP.x + piP.w * x0;
  float m0y = pmP.y + plP.x * x0 + pmP.w * x1;
  float m0z = pmP.z + plP.y * x0 + plP.z * x1 + L22 * x2;

  // --- neighbors: r0 = self, r1 = precomputed best ---
  int n1 = ((const int*)ws)[WS_NEIGH + prow];
  int nrow1 = b * KP + n1;
  const float4 plN = *(const float4*)(ws + WS_PKL + nrow1 * 4);
  const float4 piN = *(const float4*)(ws + WS_PKI + nrow1 * 4);
  const float4 pmN = *(const float4*)(ws + WS_PKM + nrow1 * 4);

  float sc[2], nx[2], ny[2], nz[2];
  {
    float dx = m0x - pmP.x, dy = m0y - pmP.y, dz = m0z - pmP.z;
    float y0 = dx * piP.x;
    float y1 = (dy - plP.x * y0) * piP.y;
    float y2 = (dz - plP.y * y0 - plP.z * y1) * piP.z;
    sc[0] = -0.5f * (y0*y0 + y1*y1 + y2*y2 + plP.w);
    nx[0] = pmP.x; ny[0] = pmP.y; nz[0] = pmP.z;
  }
  {
    float dx = m0x - pmN.x, dy = m0y - pmN.y, dz = m0z - pmN.z;
    float y0 = dx * piN.x;
    float y1 = (dy - plN.x * y0) * piN.y;
    float y2 = (dz - plN.y * y0 - plN.z * y1) * piN.z;
    sc[1] = -0.5f * (y0*y0 + y1*y1 + y2*y2 + plN.w);
    nx[1] = pmN.x; ny[1] = pmN.y; nz[1] = pmN.z;
  }
  float mxs = fmaxf(sc[0], sc[1]);
  float e0 = expf(sc[0] - mxs), e1 = expf(sc[1] - mxs);
  float inv = 1.f / (e0 + e1);
  float w0 = e0 * inv, w1 = e1 * inv;

  float mcx = w0 * nx[0] + w1 * nx[1];
  float mcy = w0 * ny[0] + w1 * ny[1];
  float mcz = w0 * nz[0] + w1 * nz[1];

  // --- Sigma_child ---
  float d0x = nx[0] - mcx, d0y = ny[0] - mcy, d0z = nz[0] - mcz;
  float d1x = nx[1] - mcx, d1y = ny[1] - mcy, d1z = nz[1] - mcz;
  const float* S0 = Sig + prow * 9;
  const float* S1 = Sig + nrow1 * 9;
  const float PHIm2 = 0.390625f; // 1.6^-2
  float Sout[9];
  float dd0[3] = {d0x, d0y, d0z};
  float dd1[3] = {d1x, d1y, d1z};
#pragma unroll
  for (int a = 0; a < 3; a++)
#pragma unroll
    for (int e = 0; e < 3; e++) {
      float v = (w0 * S0[a*3+e] + w1 * S1[a*3+e]) * PHIm2
              + w0 * dd0[a] * dd0[e] + w1 * dd1[a] * dd1[e];
      if (a == e) v += 1e-4f;
      Sout[a*3+e] = v;
    }

  if (lane == 0) {
    float* om = out + OUT_MU + wv * 3;
    om[0] = mcx; om[1] = mcy; om[2] = mcz;
    out[OUT_G + wv] = g;
    float* os = out + OUT_SIG + wv * 9;
#pragma unroll
    for (int q = 0; q < 9; q++) os[q] = Sout[q];
  }

  // --- s_child0 row: g * (w0*s_self + w1*s_nei) ---
  float s0v[4], s1v[4], ov[4];
  *(float4*)s0v = *(const float4*)(sp + prow * 256 + c4);
  *(float4*)s1v = *(const float4*)(sp + nrow1 * 256 + c4);
  float gw0 = g * w0, gw1 = g * w1;
#pragma unroll
  for (int q = 0; q < 4; q++) ov[q] = gw0 * s0v[q] + gw1 * s1v[q];
  *(float4*)(out + OUT_S + wv * 256 + c4) = *(float4*)ov;
}

// ================= Kernel F: loss_count =================
__global__ __launch_bounds__(256) void kF(const float* __restrict__ out_in,
                                          const int* __restrict__ Kt,
                                          float* __restrict__ out) {
  __shared__ float red[4][2];
  int t = threadIdx.x;
  const float* gp = out_in + OUT_G;
  float s0 = 0.f, s1 = 0.f;
  for (int it = 0; it < 32; it++) {
    s0 += gp[it * 256 + t];
    s1 += gp[KC + it * 256 + t];
  }
#pragma unroll
  for (int o = 32; o > 0; o >>= 1) {
    s0 += __shfl_xor(s0, o);
    s1 += __shfl_xor(s1, o);
  }
  int wave = t >> 6;
  if ((t & 63) == 0) { red[wave][0] = s0; red[wave][1] = s1; }
  __syncthreads();
  if (t == 0) {
    float S0 = red[0][0] + red[1][0] + red[2][0] + red[3][0];
    float S1 = red[0][1] + red[1][1] + red[2][1] + red[3][1];
    float K = (float)Kt[0];
    float l0 = S0 - K, l1 = S1 - K;
    out[OUT_LOSS] = 0.5f * (l0 * l0 + l1 * l1);
  }
}

extern "C" void kernel_launch(void* const* d_in, const int* in_sizes, int n_in,
                              void* d_out, int out_size, void* d_ws, size_t ws_size,
                              hipStream_t stream) {
  const float* s_parent   = (const float*)d_in[0];
  const float* mu_p       = (const float*)d_in[1];
  const float* Sigma_p    = (const float*)d_in[2];
  const float* mask_par   = (const float*)d_in[3];
  const float* xi_noise   = (const float*)d_in[4];
  const float* emb        = (const float*)d_in[5];
  const float* gate_ln_g  = (const float*)d_in[6];
  const float* gate_ln_b  = (const float*)d_in[7];
  const float* gate_W1    = (const float*)d_in[8];
  const float* gate_b1    = (const float*)d_in[9];
  const float* gate_W2    = (const float*)d_in[10];
  const float* gate_b2    = (const float*)d_in[11];
  const float* prior_ln_g = (const float*)d_in[12];
  const float* prior_ln_b = (const float*)d_in[13];
  const float* prior_W1   = (const float*)d_in[14];
  const float* prior_b1   = (const float*)d_in[15];
  const float* prior_W2   = (const float*)d_in[16];
  const float* prior_b2   = (const float*)d_in[17];
  const float* geom_W     = (const float*)d_in[18];
  const float* geom_b     = (const float*)d_in[19];
  const int*   K_target   = (const int*)d_in[20];

  float* ws  = (float*)d_ws;
  float* out = (float*)d_out;

  kP1<<<521, 256, 0, stream>>>(s_parent, mu_p, Sigma_p, emb, geom_W, geom_b, ws);
  kP2<<<1025, 256, 0, stream>>>(s_parent, emb, gate_ln_g, gate_ln_b, gate_W1, gate_b1,
                                prior_ln_g, prior_ln_b, prior_W1, prior_b1,
                                prior_W2, prior_b2, ws);
  kD<<<NCH / 4, 256, 0, stream>>>(s_parent, Sigma_p, mask_par, xi_noise,
                                  gate_W2, gate_b2, ws, out);
  kF<<<1, 256, 0, stream>>>(out, K_target, out);
}

// Round 10
// 146.233 us; speedup vs baseline: 1.1157x; 1.0435x over previous
//
#include <hip/hip_runtime.h>
#include <math.h>

// Problem constants (fixed by reference)
#define NPAR 2048   // B*Kp
#define KP   1024
#define MM   8
#define CC   256
#define KC   8192   // Kp*M
#define NCH  16384  // B*Kc

// ws offsets (float units). Packed AoS float4 per parent:
//  PKL = {L10, L20, L21, logdet}
//  PKI = {i0,  i1,  i2,  L00}
//  PKM = {mx,  my,  mz,  L11}
#define WS_PKL    0        // [NPAR][4]
#define WS_PKI    8192     // [NPAR][4]
#define WS_PKM    16384    // [NPAR][4]
#define WS_L22    24576    // [NPAR]
#define WS_MEANSP 26624    // [NPAR]
#define WS_SUMSQ  28672    // [NPAR]
#define WS_DOT8   30720    // [NPAR][8]
#define WS_APRIOR 47104    // [NPAR]
#define WS_EGATE  49152    // [8][256]
#define WS_UGATE  51200    // [256]
#define WS_C0GATE 51456    // [256]
#define WS_GEO    51712    // [8][3]
#define WS_MEANE  51736    // [8]
#define WS_SUMSQE 51744    // [8]
#define WS_NEIGH  51752    // [NPAR] ints
#define WS_PGATE  53824    // [NPAR][256]

// out offsets (float units)
#define OUT_S    0
#define OUT_MU   4194304
#define OUT_SIG  4243456
#define OUT_G    4390912
#define OUT_LOSS 4407296

__device__ __forceinline__ float siluf(float x){ return x / (1.f + expf(-x)); }
__device__ __forceinline__ float softplusf(float x){ return x > 20.f ? x : log1pf(expf(x)); }

// ================= Kernel P1: stats + Cholesky + misc =================
// blk 0..511   : per-parent row stats (4 parents/block, 1 wave each)
// blk 512..519 : Cholesky, thread = parent (packed float4 AoS writes)
// blk 520      : geo offsets + emb stats
__global__ __launch_bounds__(256) void kP1(const float* __restrict__ sp,
                                           const float* __restrict__ mu_p,
                                           const float* __restrict__ Sig,
                                           const float* __restrict__ emb,
                                           const float* __restrict__ geom_W,
                                           const float* __restrict__ geom_b,
                                           float* __restrict__ ws) {
  int blk = blockIdx.x;
  int t = threadIdx.x;
  if (blk < 512) {
    int pid  = blk * 4 + (t >> 6);
    int lane = t & 63;
    const float4 v = *(const float4*)(sp + pid * CC + lane * 4);
    float s  = v.x + v.y + v.z + v.w;
    float ss = v.x*v.x + v.y*v.y + v.z*v.z + v.w*v.w;
    float pd[8];
#pragma unroll
    for (int m = 0; m < 8; m++) {
      float4 e = *(const float4*)(emb + m * CC + lane * 4);
      pd[m] = v.x*e.x + v.y*e.y + v.z*e.z + v.w*e.w;
    }
#pragma unroll
    for (int o = 32; o > 0; o >>= 1) {
      s  += __shfl_xor(s, o);
      ss += __shfl_xor(ss, o);
#pragma unroll
      for (int m = 0; m < 8; m++) pd[m] += __shfl_xor(pd[m], o);
    }
    if (lane == 0) {
      ws[WS_MEANSP + pid] = s * (1.f / 256.f);
      ws[WS_SUMSQ + pid]  = ss;
#pragma unroll
      for (int m = 0; m < 8; m++) ws[WS_DOT8 + pid * 8 + m] = pd[m];
    }
  } else if (blk < 520) {
    int pid = (blk - 512) * 256 + t;   // 0..2047
    const float* S = Sig + pid * 9;
    float a00 = S[0] + 1e-6f, a10 = S[3], a11 = S[4] + 1e-6f;
    float a20 = S[6], a21 = S[7], a22 = S[8] + 1e-6f;
    float L00 = sqrtf(a00); float i0 = 1.f / L00;
    float L10 = a10 * i0, L20 = a20 * i0;
    float L11 = sqrtf(a11 - L10 * L10); float i1 = 1.f / L11;
    float L21 = (a21 - L20 * L10) * i1;
    float L22 = sqrtf(a22 - L20 * L20 - L21 * L21); float i2 = 1.f / L22;
    float logdet = 2.f * logf(L00 * L11 * L22);
    float4 pkl = {L10, L20, L21, logdet};
    float4 pki = {i0, i1, i2, L00};
    float4 pkm = {mu_p[pid*3+0], mu_p[pid*3+1], mu_p[pid*3+2], L11};
    *(float4*)(ws + WS_PKL + pid * 4) = pkl;
    *(float4*)(ws + WS_PKI + pid * 4) = pki;
    *(float4*)(ws + WS_PKM + pid * 4) = pkm;
    ws[WS_L22 + pid] = L22;
  } else {
    if (t < 192) {
      int o = t >> 3, lane8 = t & 7;
      int m = o / 3, d = o % 3;
      float acc = 0.f;
      for (int k = lane8; k < 256; k += 8) acc += emb[m * 256 + k] * geom_W[k * 3 + d];
      acc += __shfl_xor(acc, 1); acc += __shfl_xor(acc, 2); acc += __shfl_xor(acc, 4);
      if (lane8 == 0) ws[WS_GEO + o] = acc + geom_b[d];
    } else {
      int o = (t - 192) >> 3, lane8 = t & 7;
      if (o < 8) {
        float s = 0.f, ss = 0.f;
        for (int k = lane8; k < 256; k += 8) { float e = emb[o * 256 + k]; s += e; ss += e * e; }
        s  += __shfl_xor(s, 1);  s  += __shfl_xor(s, 2);  s  += __shfl_xor(s, 4);
        ss += __shfl_xor(ss, 1); ss += __shfl_xor(ss, 2); ss += __shfl_xor(ss, 4);
        if (lane8 == 0) { ws[WS_MEANE + o] = s * (1.f / 256.f); ws[WS_SUMSQE + o] = ss; }
      }
    }
  }
}

// ================= Kernel P2: neighbor search + head GEMMs =================
// blk 0..511   : best-neighbor search (packed float4 loads, no recompute)
// blk 512..1025: head GEMMs: gate-P (256) / prior head (256) / E_gate (1) / u,c0 (1)
__global__ __launch_bounds__(256) void kP2(const float* __restrict__ sp,
                                           const float* __restrict__ emb,
                                           const float* __restrict__ g_ln_g,
                                           const float* __restrict__ g_ln_b,
                                           const float* __restrict__ gW1,
                                           const float* __restrict__ gb1,
                                           const float* __restrict__ p_ln_g,
                                           const float* __restrict__ p_ln_b,
                                           const float* __restrict__ pW1,
                                           const float* __restrict__ pb1,
                                           const float* __restrict__ pW2,
                                           const float* __restrict__ pb2,
                                           float* __restrict__ ws) {
  __shared__ float xs[8][256];
  __shared__ float red[4][8];
  __shared__ float redS[4][8];
  __shared__ float redQ[4][8];
  __shared__ float mv[2][8];
  int blk = blockIdx.x;
  int t = threadIdx.x;

  if (blk < 512) {
    // ---- best neighbor (excluding self) ----
    int wv = blk * 4 + (t >> 6);   // parent row 0..2047
    int lane = t & 63;
    int b = wv >> 10;
    int j = wv & (KP - 1);
    const float4 qm = *(const float4*)(ws + WS_PKM + wv * 4);
    float qx = qm.x, qy = qm.y, qz = qm.z;
    float best = -3.4e38f; int bidx = 1 << 30;
    for (int it = 0; it < 16; it++) {
      int k = it * 64 + lane;
      int idx = b * KP + k;
      float4 pl = *(const float4*)(ws + WS_PKL + idx * 4);  // L10,L20,L21,ld
      float4 pi = *(const float4*)(ws + WS_PKI + idx * 4);  // i0,i1,i2,L00
      float4 pm = *(const float4*)(ws + WS_PKM + idx * 4);  // mx,my,mz,L11
      float dx = qx - pm.x, dy = qy - pm.y, dz = qz - pm.z;
      float y0 = dx * pi.x;
      float y1 = (dy - pl.x * y0) * pi.y;
      float y2 = (dz - pl.y * y0 - pl.z * y1) * pi.z;
      float sc = -0.5f * (y0*y0 + y1*y1 + y2*y2 + pl.w);
      if (k == j) sc = -3.4e38f;
      if (sc > best || (sc == best && k < bidx)) { best = sc; bidx = k; }
    }
#pragma unroll
    for (int o = 32; o > 0; o >>= 1) {
      float ob = __shfl_xor(best, o);
      int   oi = __shfl_xor(bidx, o);
      if (ob > best || (ob == best && oi < bidx)) { best = ob; bidx = oi; }
    }
    if (lane == 0) ((int*)ws)[WS_NEIGH + wv] = bidx;
  } else {
    // ---- head GEMMs ----
    int cblk = blk - 512;
    bool prior = (cblk >= 256 && cblk < 512);
    const float* W1 = prior ? pW1 : gW1;

    if (cblk < 256) {
      int base = cblk * 8;
      float g = g_ln_g[t];
#pragma unroll
      for (int r = 0; r < 8; r++) xs[r][t] = sp[(base + r) * 256 + t] * g;
    } else if (cblk < 512) {
      int base = (cblk - 256) * 8;
      float vr[8], s1[8], s2[8];
#pragma unroll
      for (int r = 0; r < 8; r++) {
        vr[r] = sp[(base + r) * 256 + t];
        s1[r] = vr[r];
        s2[r] = vr[r] * vr[r];
      }
#pragma unroll
      for (int o = 32; o > 0; o >>= 1) {
#pragma unroll
        for (int r = 0; r < 8; r++) { s1[r] += __shfl_xor(s1[r], o); s2[r] += __shfl_xor(s2[r], o); }
      }
      int wave = t >> 6;
      if ((t & 63) == 0) {
#pragma unroll
        for (int r = 0; r < 8; r++) { redS[wave][r] = s1[r]; redQ[wave][r] = s2[r]; }
      }
      __syncthreads();
      if (t < 8) {
        float sum = redS[0][t] + redS[1][t] + redS[2][t] + redS[3][t];
        float sq  = redQ[0][t] + redQ[1][t] + redQ[2][t] + redQ[3][t];
        float mean = sum * (1.f / 256.f);
        float var  = sq * (1.f / 256.f) - mean * mean;
        mv[0][t] = mean;
        mv[1][t] = rsqrtf(var + 1e-5f);
      }
      __syncthreads();
      float pg = p_ln_g[t], pbv = p_ln_b[t];
#pragma unroll
      for (int r = 0; r < 8; r++)
        xs[r][t] = (vr[r] - mv[0][r]) * mv[1][r] * pg + pbv;
    } else if (cblk == 512) {
      float g = g_ln_g[t];
#pragma unroll
      for (int r = 0; r < 8; r++) xs[r][t] = emb[r * 256 + t] * g;
    } else {
      xs[0][t] = g_ln_g[t];
      xs[1][t] = g_ln_b[t];
#pragma unroll
      for (int r = 2; r < 8; r++) xs[r][t] = 0.f;
    }
    __syncthreads();

    // k-unrolled x4: ds_read_b128 for xs, 4 coalesced global loads for W1
    float acc[8] = {0,0,0,0,0,0,0,0};
    for (int k4 = 0; k4 < 256; k4 += 4) {
      float w0 = W1[(k4+0) * 256 + t];
      float w1 = W1[(k4+1) * 256 + t];
      float w2 = W1[(k4+2) * 256 + t];
      float w3 = W1[(k4+3) * 256 + t];
#pragma unroll
      for (int r = 0; r < 8; r++) {
        float4 x4 = *(const float4*)&xs[r][k4];
        acc[r] += x4.x * w0 + x4.y * w1 + x4.z * w2 + x4.w * w3;
      }
    }

    if (cblk < 256) {
      int base = cblk * 8;
#pragma unroll
      for (int r = 0; r < 8; r++) ws[WS_PGATE + (base + r) * 256 + t] = acc[r];
    } else if (cblk < 512) {
      int base = (cblk - 256) * 8;
      float b1 = pb1[t], w2 = pW2[t];
      float tv[8];
#pragma unroll
      for (int r = 0; r < 8; r++) {
        float h = acc[r] + b1;
        tv[r] = siluf(h) * w2;
      }
#pragma unroll
      for (int o = 32; o > 0; o >>= 1) {
#pragma unroll
        for (int r = 0; r < 8; r++) tv[r] += __shfl_xor(tv[r], o);
      }
      int wave = t >> 6;
      if ((t & 63) == 0) {
#pragma unroll
        for (int r = 0; r < 8; r++) red[wave][r] = tv[r];
      }
      __syncthreads();
      if (t < 8) {
        float sum = red[0][t] + red[1][t] + red[2][t] + red[3][t] + pb2[0];
        ws[WS_APRIOR + base + t] = softplusf(sum);
      }
    } else if (cblk == 512) {
#pragma unroll
      for (int r = 0; r < 8; r++) ws[WS_EGATE + r * 256 + t] = acc[r];
    } else {
      ws[WS_UGATE + t]  = acc[0];
      ws[WS_C0GATE + t] = acc[1] + gb1[t];
    }
  }
}

// ================= Kernel D: per-child everything (one wave per child) =================
// NO device-scope atomics / fences here (round 3: per-block __threadfence
// across non-coherent XCD L2s serialized the kernel, 142 us vs ~12 us).
__global__ __launch_bounds__(256) void kD(const float* __restrict__ sp,
                                          const float* __restrict__ Sig,
                                          const float* __restrict__ mask,
                                          const float* __restrict__ xi_noise,
                                          const float* __restrict__ gW2,
                                          const float* __restrict__ gb2,
                                          const float* __restrict__ ws,
                                          float* __restrict__ out) {
  int wv   = blockIdx.x * 4 + (threadIdx.x >> 6);  // child 0..16383 (= b*Kc+i)
  int lane = threadIdx.x & 63;
  int b = wv >> 13;
  int i = wv & (KC - 1);
  int j = i >> 3;
  int m = i & 7;
  int prow = b * KP + j;

  // --- LN stats for gate_in row ---
  float mean_x = ws[WS_MEANSP + prow] + ws[WS_MEANE + m];
  float Ex2 = ws[WS_SUMSQ + prow] + 2.f * ws[WS_DOT8 + prow * 8 + m] + ws[WS_SUMSQE + m];
  float var = Ex2 * (1.f / 256.f) - mean_x * mean_x;
  float rstd = rsqrtf(var + 1e-5f);

  // --- gate head epilogue: pre = (P + E - mean*u)*rstd + c0; silu; dot W2 ---
  int c4 = lane * 4;
  float Pv[4], Ev[4], Uv[4], C0v[4], W2v[4];
  *(float4*)Pv  = *(const float4*)(ws + WS_PGATE + prow * 256 + c4);
  *(float4*)Ev  = *(const float4*)(ws + WS_EGATE + m * 256 + c4);
  *(float4*)Uv  = *(const float4*)(ws + WS_UGATE + c4);
  *(float4*)C0v = *(const float4*)(ws + WS_C0GATE + c4);
  *(float4*)W2v = *(const float4*)(gW2 + c4);
  float partial = 0.f;
#pragma unroll
  for (int q = 0; q < 4; q++) {
    float pre = (Pv[q] + Ev[q] - mean_x * Uv[q]) * rstd + C0v[q];
    partial += siluf(pre) * W2v[q];
  }
#pragma unroll
  for (int o = 32; o > 0; o >>= 1) partial += __shfl_xor(partial, o);
  float aP = ws[WS_APRIOR + prow];
  float bval = partial + gb2[0] + 0.5f * logf(aP + 1e-8f);
  float g = (1.f / (1.f + expf(-bval))) * mask[prow];

  // --- parent packed state ---
  const float4 plP = *(const float4*)(ws + WS_PKL + prow * 4);  // L10,L20,L21,ld
  const float4 piP = *(const float4*)(ws + WS_PKI + prow * 4);  // i0,i1,i2,L00
  const float4 pmP = *(const float4*)(ws + WS_PKM + prow * 4);  // mx,my,mz,L11
  float L22 = ws[WS_L22 + prow];

  // --- mu0 = mu_p + Lp @ (xi_noise + geo[m]) ---
  int xbase = (prow * 8 + m) * 3;
  float x0 = xi_noise[xbase + 0] + ws[WS_GEO + m * 3 + 0];
  float x1 = xi_noise[xbase + 1] + ws[WS_GEO + m * 3 + 1];
  float x2 = xi_noise[xbase + 2] + ws[WS_GEO + m * 3 + 2];
  float m0x = pmP.x + piP.w * x0;
  float m0y = pmP.y + plP.x * x0 + pmP.w * x1;
  float m0z = pmP.z + plP.y * x0 + plP.z * x1 + L22 * x2;

  // --- neighbors: r0 = self, r1 = precomputed best ---
  int n1 = ((const int*)ws)[WS_NEIGH + prow];
  int nrow1 = b * KP + n1;
  const float4 plN = *(const float4*)(ws + WS_PKL + nrow1 * 4);
  const float4 piN = *(const float4*)(ws + WS_PKI + nrow1 * 4);
  const float4 pmN = *(const float4*)(ws + WS_PKM + nrow1 * 4);

  float sc[2], nx[2], ny[2], nz[2];
  {
    float dx = m0x - pmP.x, dy = m0y - pmP.y, dz = m0z - pmP.z;
    float y0 = dx * piP.x;
    float y1 = (dy - plP.x * y0) * piP.y;
    float y2 = (dz - plP.y * y0 - plP.z * y1) * piP.z;
    sc[0] = -0.5f * (y0*y0 + y1*y1 + y2*y2 + plP.w);
    nx[0] = pmP.x; ny[0] = pmP.y; nz[0] = pmP.z;
  }
  {
    float dx = m0x - pmN.x, dy = m0y - pmN.y, dz = m0z - pmN.z;
    float y0 = dx * piN.x;
    float y1 = (dy - plN.x * y0) * piN.y;
    float y2 = (dz - plN.y * y0 - plN.z * y1) * piN.z;
    sc[1] = -0.5f * (y0*y0 + y1*y1 + y2*y2 + plN.w);
    nx[1] = pmN.x; ny[1] = pmN.y; nz[1] = pmN.z;
  }
  float mxs = fmaxf(sc[0], sc[1]);
  float e0 = expf(sc[0] - mxs), e1 = expf(sc[1] - mxs);
  float inv = 1.f / (e0 + e1);
  float w0 = e0 * inv, w1 = e1 * inv;

  float mcx = w0 * nx[0] + w1 * nx[1];
  float mcy = w0 * ny[0] + w1 * ny[1];
  float mcz = w0 * nz[0] + w1 * nz[1];

  // --- Sigma_child ---
  float d0x = nx[0] - mcx, d0y = ny[0] - mcy, d0z = nz[0] - mcz;
  float d1x = nx[1] - mcx, d1y = ny[1] - mcy, d1z = nz[1] - mcz;
  const float* S0 = Sig + prow * 9;
  const float* S1 = Sig + nrow1 * 9;
  const float PHIm2 = 0.390625f; // 1.6^-2
  float Sout[9];
  float dd0[3] = {d0x, d0y, d0z};
  float dd1[3] = {d1x, d1y, d1z};
#pragma unroll
  for (int a = 0; a < 3; a++)
#pragma unroll
    for (int e = 0; e < 3; e++) {
      float v = (w0 * S0[a*3+e] + w1 * S1[a*3+e]) * PHIm2
              + w0 * dd0[a] * dd0[e] + w1 * dd1[a] * dd1[e];
      if (a == e) v += 1e-4f;
      Sout[a*3+e] = v;
    }

  if (lane == 0) {
    float* om = out + OUT_MU + wv * 3;
    om[0] = mcx; om[1] = mcy; om[2] = mcz;
    out[OUT_G + wv] = g;
    float* os = out + OUT_SIG + wv * 9;
#pragma unroll
    for (int q = 0; q < 9; q++) os[q] = Sout[q];
  }

  // --- s_child0 row: g * (w0*s_self + w1*s_nei) ---
  float s0v[4], s1v[4], ov[4];
  *(float4*)s0v = *(const float4*)(sp + prow * 256 + c4);
  *(float4*)s1v = *(const float4*)(sp + nrow1 * 256 + c4);
  float gw0 = g * w0, gw1 = g * w1;
#pragma unroll
  for (int q = 0; q < 4; q++) ov[q] = gw0 * s0v[q] + gw1 * s1v[q];
  *(float4*)(out + OUT_S + wv * 256 + c4) = *(float4*)ov;
}

// ================= Kernel F: loss_count =================
__global__ __launch_bounds__(256) void kF(const float* __restrict__ out_in,
                                          const int* __restrict__ Kt,
                                          float* __restrict__ out) {
  __shared__ float red[4][2];
  int t = threadIdx.x;
  const float* gp = out_in + OUT_G;
  float s0 = 0.f, s1 = 0.f;
  for (int it = 0; it < 32; it++) {
    s0 += gp[it * 256 + t];
    s1 += gp[KC + it * 256 + t];
  }
#pragma unroll
  for (int o = 32; o > 0; o >>= 1) {
    s0 += __shfl_xor(s0, o);
    s1 += __shfl_xor(s1, o);
  }
  int wave = t >> 6;
  if ((t & 63) == 0) { red[wave][0] = s0; red[wave][1] = s1; }
  __syncthreads();
  if (t == 0) {
    float S0 = red[0][0] + red[1][0] + red[2][0] + red[3][0];
    float S1 = red[0][1] + red[1][1] + red[2][1] + red[3][1];
    float K = (float)Kt[0];
    float l0 = S0 - K, l1 = S1 - K;
    out[OUT_LOSS] = 0.5f * (l0 * l0 + l1 * l1);
  }
}

extern "C" void kernel_launch(void* const* d_in, const int* in_sizes, int n_in,
                              void* d_out, int out_size, void* d_ws, size_t ws_size,
                              hipStream_t stream) {
  const float* s_parent   = (const float*)d_in[0];
  const float* mu_p       = (const float*)d_in[1];
  const float* Sigma_p    = (const float*)d_in[2];
  const float* mask_par   = (const float*)d_in[3];
  const float* xi_noise   = (const float*)d_in[4];
  const float* emb        = (const float*)d_in[5];
  const float* gate_ln_g  = (const float*)d_in[6];
  const float* gate_ln_b  = (const float*)d_in[7];
  const float* gate_W1    = (const float*)d_in[8];
  const float* gate_b1    = (const float*)d_in[9];
  const float* gate_W2    = (const float*)d_in[10];
  const float* gate_b2    = (const float*)d_in[11];
  const float* prior_ln_g = (const float*)d_in[12];
  const float* prior_ln_b = (const float*)d_in[13];
  const float* prior_W1   = (const float*)d_in[14];
  const float* prior_b1   = (const float*)d_in[15];
  const float* prior_W2   = (const float*)d_in[16];
  const float* prior_b2   = (const float*)d_in[17];
  const float* geom_W     = (const float*)d_in[18];
  const float* geom_b     = (const float*)d_in[19];
  const int*   K_target   = (const int*)d_in[20];

  float* ws  = (float*)d_ws;
  float* out = (float*)d_out;

  kP1<<<521, 256, 0, stream>>>(s_parent, mu_p, Sigma_p, emb, geom_W, geom_b, ws);
  kP2<<<1026, 256, 0, stream>>>(s_parent, emb, gate_ln_g, gate_ln_b, gate_W1, gate_b1,
                                prior_ln_g, prior_ln_b, prior_W1, prior_b1,
                                prior_W2, prior_b2, ws);
  kD<<<NCH / 4, 256, 0, stream>>>(s_parent, Sigma_p, mask_par, xi_noise,
                                  gate_W2, gate_b2, ws, out);
  kF<<<1, 256, 0, stream>>>(out, K_target, out);
}